// Round 3
// baseline (399.390 us; speedup 1.0000x reference)
//
#include <hip/hip_runtime.h>

#define DIM 128
#define CLS 40
#define PSTR 160  // padded activation row stride (4 chunks x 40 bf16)

typedef __attribute__((ext_vector_type(8))) short bf16x8;
typedef __attribute__((ext_vector_type(4))) float f32x4;

__device__ __forceinline__ ushort f2bf(float f) {
  uint u = __float_as_uint(f);
  u += 0x7FFFu + ((u >> 16) & 1u);
  return (ushort)(u >> 16);
}
__device__ __forceinline__ float bf2f(ushort h) {
  return __uint_as_float(((uint)h) << 16);
}

__device__ __forceinline__ void gl16(const void* g, void* l) {
  __builtin_amdgcn_global_load_lds((const __attribute__((address_space(1))) unsigned*)g,
                                   (__attribute__((address_space(3))) unsigned*)l, 16, 0, 0);
}

// ---------------- prep: zero stats/cnt, build weight images, convert x -> padded bf16 ----------------

__device__ __forceinline__ void build_img(ushort* __restrict__ img, const float* __restrict__ Wl,
                                          const float* __restrict__ Wr, int ncol, int BJ, int t) {
  int kq = t % 40;
  int u = t / 40;
  int j = u % BJ;
  u /= BJ;
  int hl = u & 1;
  int kc = u >> 1;
  int k = kc * 32 + kq;
  float v = 0.f;
  if (kq < 32 && j < ncol) v = (k < 128) ? Wl[j * 128 + k] : Wr[j * 128 + (k - 128)];
  ushort hi = f2bf(v);
  img[t] = hl ? f2bf(v - bf2f(hi)) : hi;
}

#define IMG1 (8 * 2 * 128 * 40)
#define IMG2 (8 * 2 * 48 * 40)

__global__ void prep_kernel(const float* __restrict__ x, const float* __restrict__ Wl01,
                            const float* __restrict__ Wr01, const float* __restrict__ Wl2,
                            const float* __restrict__ Wr2, ushort* __restrict__ img01,
                            ushort* __restrict__ img2, ushort* __restrict__ xbf,
                            float* __restrict__ stats2, int* __restrict__ cnt, int N) {
  int idx = blockIdx.x * 256 + threadIdx.x;
  int b0 = 512;
  int b1 = b0 + N;
  int b2 = b1 + IMG1;
  int b3 = b2 + IMG1;
  int b4 = b3 + IMG2;
  int b5 = b4 + N * 16;
  if (idx < b0) { stats2[idx] = 0.f; return; }
  if (idx < b1) { cnt[idx - b0] = 0; return; }
  if (idx < b2) { build_img(img01, Wl01, Wr01, 128, 128, idx - b1); return; }
  if (idx < b3) { build_img(img01 + IMG1, Wl01 + 128 * 128, Wr01 + 128 * 128, 128, 128, idx - b2); return; }
  if (idx < b4) { build_img(img2, Wl2, Wr2, 40, 48, idx - b3); return; }
  if (idx < b5) {
    int t = idx - b4;
    int n = t >> 4, part = t & 15;
    const float4* xp = (const float4*)&x[(size_t)n * DIM + part * 8];
    float4 v0 = xp[0], v1 = xp[1];
    union { ushort u[8]; uint4 v; } pk;
    pk.u[0] = f2bf(v0.x); pk.u[1] = f2bf(v0.y); pk.u[2] = f2bf(v0.z); pk.u[3] = f2bf(v0.w);
    pk.u[4] = f2bf(v1.x); pk.u[5] = f2bf(v1.y); pk.u[6] = f2bf(v1.z); pk.u[7] = f2bf(v1.w);
    *(uint4*)&xbf[(size_t)n * PSTR + (part >> 2) * 40 + (part & 3) * 8] = pk.v;
    if (part < 4) {
      uint4 z = make_uint4(0, 0, 0, 0);
      *(uint4*)&xbf[(size_t)n * PSTR + part * 40 + 32] = z;
    }
  }
}

// ---------------- CSR build ----------------

__global__ void hist_kernel(const int* __restrict__ ei, const float* __restrict__ conf,
                            int* __restrict__ cnt, int E) {
  int e = blockIdx.x * 256 + threadIdx.x;
  if (e < E && conf[e] > 0.5f) atomicAdd(&cnt[ei[E + e]], 1);
}

__global__ __launch_bounds__(1024) void scan_kernel(const int* __restrict__ cnt,
                                                    int* __restrict__ off,
                                                    int* __restrict__ pos, int n) {
  __shared__ int wsum[16];
  __shared__ int carry_s;
  int lane = threadIdx.x & 63;
  int wid = threadIdx.x >> 6;
  if (threadIdx.x == 0) carry_s = 0;
  __syncthreads();
  int n4 = (n + 3) >> 2;
  for (int base = 0; base < n4; base += 1024) {
    int i4 = base + (int)threadIdx.x;
    int4 v = make_int4(0, 0, 0, 0);
    int i0 = i4 * 4;
    if (i0 + 3 < n) {
      v = *(const int4*)&cnt[i0];
    } else if (i0 < n) {
      v.x = cnt[i0];
      if (i0 + 1 < n) v.y = cnt[i0 + 1];
      if (i0 + 2 < n) v.z = cnt[i0 + 2];
    }
    int s4 = v.x + v.y + v.z + v.w;
    int s = s4;
#pragma unroll
    for (int o = 1; o < 64; o <<= 1) {
      int t = __shfl_up(s, o);
      if (lane >= o) s += t;
    }
    if (lane == 63) wsum[wid] = s;
    __syncthreads();
    if (wid == 0) {
      int w = (lane < 16) ? wsum[lane] : 0;
#pragma unroll
      for (int o = 1; o < 16; o <<= 1) {
        int t = __shfl_up(w, o);
        if (lane >= o) w += t;
      }
      if (lane < 16) wsum[lane] = w;
    }
    __syncthreads();
    int carry = carry_s;
    int wbase = (wid == 0) ? 0 : wsum[wid - 1];
    int excl = carry + wbase + s - s4;
    if (i0 < n) {
      int e0 = excl, e1 = e0 + v.x, e2 = e1 + v.y, e3 = e2 + v.z;
      off[i0] = e0; pos[i0] = e0;
      if (i0 + 1 < n) { off[i0 + 1] = e1; pos[i0 + 1] = e1; }
      if (i0 + 2 < n) { off[i0 + 2] = e2; pos[i0 + 2] = e2; }
      if (i0 + 3 < n) { off[i0 + 3] = e3; pos[i0 + 3] = e3; }
    }
    int tot = wsum[15];
    __syncthreads();
    if (threadIdx.x == 0) carry_s = carry + tot;
    __syncthreads();
  }
  if (threadIdx.x == 0) off[n] = carry_s;
}

__global__ void fill_kernel(const int* __restrict__ ei, const float* __restrict__ conf,
                            int* __restrict__ pos, int* __restrict__ esrc, int E) {
  int e = blockIdx.x * 256 + threadIdx.x;
  if (e < E && conf[e] > 0.5f) {
    int p = atomicAdd(&pos[ei[E + e]], 1);
    esrc[p] = ei[e];
  }
}

// ---------------- enc (+ fused BN+relu of previous linear output) ----------------

__global__ __launch_bounds__(256) void enc_kernel(const ushort* __restrict__ src,
                                                  const int* __restrict__ labels,
                                                  const float* __restrict__ We,
                                                  const float* __restrict__ be,
                                                  float* __restrict__ enc,
                                                  ushort* __restrict__ hbf,
                                                  const float* __restrict__ stats,
                                                  const float* __restrict__ gamma,
                                                  const float* __restrict__ beta,
                                                  int padded, int useBN, int N) {
  int wid = threadIdx.x >> 6;
  int lane = threadIdx.x & 63;
  int n = blockIdx.x * 4 + wid;
  if (n >= N) return;
  int c = labels[n];
  int sc = c < 0 ? 0 : c;
  int d0 = lane, d1 = 64 + lane;
  size_t base = (size_t)n * (padded ? PSTR : DIM);
  int o0 = padded ? ((d0 >> 5) * 40 + (d0 & 31)) : d0;
  int o1 = padded ? ((d1 >> 5) * 40 + (d1 & 31)) : d1;
  float h0 = bf2f(src[base + o0]);
  float h1 = bf2f(src[base + o1]);
  if (useBN) {
    float inv = 1.f / (float)N;
    float mu0 = stats[d0] * inv, mu1 = stats[d1] * inv;
    float va0 = stats[DIM + d0] * inv - mu0 * mu0;
    float va1 = stats[DIM + d1] * inv - mu1 * mu1;
    h0 = fmaxf(fmaf(gamma[d0] * (h0 - mu0), rsqrtf(va0 + 1e-5f), beta[d0]), 0.f);
    h1 = fmaxf(fmaf(gamma[d1] * (h1 - mu1), rsqrtf(va1 + 1e-5f), beta[d1]), 0.f);
    size_t ob = (size_t)n * PSTR;
    hbf[ob + (d0 >> 5) * 40 + (d0 & 31)] = f2bf(h0);
    hbf[ob + (d1 >> 5) * 40 + (d1 & 31)] = f2bf(h1);
    if (lane < 32) hbf[ob + (lane >> 3) * 40 + 32 + (lane & 7)] = 0;
  }
  const float* wb = We + (size_t)sc * 4 * DIM;
  float p0 = wb[0 * DIM + lane] * h0 + wb[0 * DIM + 64 + lane] * h1;
  float p1 = wb[1 * DIM + lane] * h0 + wb[1 * DIM + 64 + lane] * h1;
  float p2 = wb[2 * DIM + lane] * h0 + wb[2 * DIM + 64 + lane] * h1;
  float p3 = wb[3 * DIM + lane] * h0 + wb[3 * DIM + 64 + lane] * h1;
#pragma unroll
  for (int o = 32; o > 0; o >>= 1) {
    p0 += __shfl_xor(p0, o);
    p1 += __shfl_xor(p1, o);
    p2 += __shfl_xor(p2, o);
    p3 += __shfl_xor(p3, o);
  }
  if (lane == 0) {
    const float* bb = be + sc * 4;
    float4 r;
    r.x = (c < 0) ? 0.f : fmaxf(p0 + bb[0], 0.f);
    r.y = (c < 0) ? 0.f : fmaxf(p1 + bb[1], 0.f);
    r.z = (c < 0) ? 0.f : fmaxf(p2 + bb[2], 0.f);
    r.w = (c < 0) ? 0.f : fmaxf(p3 + bb[3], 0.f);
    *(float4*)&enc[n * 4] = r;
  }
}

// ---------------- agg: scatter-mean of routed decoder over selected edges ----------------

__global__ __launch_bounds__(256) void agg_kernel(const float* __restrict__ enc,
                                                  const int* __restrict__ labels,
                                                  const int* __restrict__ off,
                                                  const int* __restrict__ esrc,
                                                  const float* __restrict__ Wd,
                                                  const float* __restrict__ bd,
                                                  ushort* __restrict__ aggbf, int N) {
  int half = threadIdx.x >> 7;
  int d = threadIdx.x & 127;
  int n = blockIdx.x * 2 + half;
  if (n >= N) return;
  int c = labels[n];
  int j0 = off[n], j1 = off[n + 1];
  int cnt = j1 - j0;
  float outv = 0.f;
  if (c >= 0 && cnt > 0) {
    const float4 w = *(const float4*)&Wd[((size_t)c * DIM + d) * 4];
    const float bb = bd[(size_t)c * DIM + d];
    float acc = 0.f;
    for (int j = j0; j < j1; ++j) {
      int s = esrc[j];
      float4 m = *(const float4*)&enc[s * 4];
      float v = fmaf(w.x, m.x, fmaf(w.y, m.y, fmaf(w.z, m.z, fmaf(w.w, m.w, bb))));
      acc += fmaxf(v, 0.f);
    }
    outv = acc / (float)cnt;
  }
  size_t ob = (size_t)n * PSTR;
  aggbf[ob + (d >> 5) * 40 + (d & 31)] = f2bf(outv);
  if (d < 32) aggbf[ob + (d >> 3) * 40 + 32 + (d & 7)] = 0;
}

// ---------------- GEMM: out[n,j] = bias[j] + sum_k [agg|h][n,k]*W[j,k] ----------------
// BM=64, 4 waves. A = bf16 padded activations (global_load_lds direct),
// B = prebuilt split hi/lo image (global_load_lds direct), 2-phase dbuf.

template <int NCOL>
__global__ __launch_bounds__(256) void linear_mfma(const ushort* __restrict__ Abf,
                                                   const ushort* __restrict__ Hbf,
                                                   const ushort* __restrict__ img,
                                                   const float* __restrict__ bias,
                                                   ushort* __restrict__ h1bf,
                                                   float* __restrict__ outf,
                                                   float* __restrict__ stats, int N) {
  constexpr int BJ = (NCOL == 128) ? 128 : 48;
  constexpr int BCH = 2 * BJ * 40;       // elems per B chunk
  constexpr int NBLD = BCH * 2 / 16;     // 16B lane-loads per B chunk
  constexpr int MF = (NCOL == 128) ? 2 : 1;
  constexpr int NF = (NCOL == 128) ? 4 : 3;
  __shared__ __align__(16) ushort Alds[2][64 * 40];
  __shared__ __align__(16) ushort Blds[2][BCH];
  const int tid = threadIdx.x;
  const int w = tid >> 6, l = tid & 63;
  const int r0 = blockIdx.x * 64;
  const int wrow = (NCOL == 128) ? (w >> 1) * 32 : w * 16;
  const int wcol = (NCOL == 128) ? (w & 1) * 64 : 0;

  f32x4 acc[MF][NF];
#pragma unroll
  for (int m = 0; m < MF; ++m)
#pragma unroll
    for (int n = 0; n < NF; ++n) acc[m][n] = (f32x4){0.f, 0.f, 0.f, 0.f};

  auto stageA = [&](int buf, int kc) {
    const ushort* src = (kc < 4) ? Abf : Hbf;
    const int coff = (kc & 3) * 80;  // byte offset of chunk within padded row
#pragma unroll
    for (int i = 0; i < 2; ++i) {
      int idx = i * 256 + tid;
      if (idx < 320) {
        int row = idx / 5, part = idx - row * 5;
        if (r0 + row < N)
          gl16((const char*)src + (size_t)(r0 + row) * 320 + coff + part * 16,
               (char*)&Alds[buf][0] + idx * 16);
      }
    }
  };
  auto stageB = [&](int buf, int kc) {
    const char* src = (const char*)(img + (size_t)kc * BCH);
#pragma unroll
    for (int i = 0; i < (NBLD + 255) / 256; ++i) {
      int idx = i * 256 + tid;
      if ((NBLD % 256 == 0) || idx < NBLD)
        gl16(src + idx * 16, (char*)&Blds[buf][0] + idx * 16);
    }
  };

  stageA(0, 0);
  stageB(0, 0);
  __syncthreads();
  int cur = 0;
  const int kg = (l >> 4) * 8;
  for (int kc = 0; kc < 8; ++kc) {
    if (kc < 7) {
      stageA(cur ^ 1, kc + 1);
      stageB(cur ^ 1, kc + 1);
    }
    bf16x8 a[MF], bh[NF], bl[NF];
#pragma unroll
    for (int m = 0; m < MF; ++m)
      a[m] = *(const bf16x8*)&Alds[cur][(wrow + m * 16 + (l & 15)) * 40 + kg];
#pragma unroll
    for (int n = 0; n < NF; ++n) {
      int col = wcol + n * 16 + (l & 15);
      bh[n] = *(const bf16x8*)&Blds[cur][col * 40 + kg];
      bl[n] = *(const bf16x8*)&Blds[cur][BJ * 40 + col * 40 + kg];
    }
#pragma unroll
    for (int m = 0; m < MF; ++m)
#pragma unroll
      for (int n = 0; n < NF; ++n) {
        acc[m][n] = __builtin_amdgcn_mfma_f32_16x16x32_bf16(a[m], bh[n], acc[m][n], 0, 0, 0);
        acc[m][n] = __builtin_amdgcn_mfma_f32_16x16x32_bf16(a[m], bl[n], acc[m][n], 0, 0, 0);
      }
    __syncthreads();
    cur ^= 1;
  }

  if constexpr (NCOL == 128) {
#pragma unroll
    for (int n = 0; n < NF; ++n) {
      int col = wcol + n * 16 + (l & 15);
      float bv = bias[col];
      float s = 0.f, q2 = 0.f;
#pragma unroll
      for (int m = 0; m < MF; ++m) {
#pragma unroll
        for (int r = 0; r < 4; ++r) {
          int row = r0 + wrow + m * 16 + (l >> 4) * 4 + r;
          if (row < N) {
            float v = acc[m][n][r] + bv;
            h1bf[(size_t)row * DIM + col] = f2bf(v);
            s += v;
            q2 = fmaf(v, v, q2);
          }
        }
      }
      s += __shfl_xor(s, 16); s += __shfl_xor(s, 32);
      q2 += __shfl_xor(q2, 16); q2 += __shfl_xor(q2, 32);
      if (l < 16) {
        atomicAdd(&stats[col], s);
        atomicAdd(&stats[DIM + col], q2);
      }
    }
  } else {
#pragma unroll
    for (int n = 0; n < NF; ++n) {
      int col = n * 16 + (l & 15);
      if (col < NCOL) {
        float bv = bias[col];
#pragma unroll
        for (int r = 0; r < 4; ++r) {
          int row = r0 + wrow + (l >> 4) * 4 + r;
          if (row < N) outf[(size_t)row * NCOL + col] = acc[0][n][r] + bv;
        }
      }
    }
  }
}

// ---------------- host ----------------

extern "C" void kernel_launch(void* const* d_in, const int* in_sizes, int n_in,
                              void* d_out, int out_size, void* d_ws, size_t ws_size,
                              hipStream_t stream) {
  const float* x      = (const float*)d_in[0];
  const int*   ei     = (const int*)d_in[1];
  const int*   labels = (const int*)d_in[2];
  const float* conf   = (const float*)d_in[3];
  const float* W_enc  = (const float*)d_in[4];
  const float* b_enc  = (const float*)d_in[5];
  const float* W_dec  = (const float*)d_in[6];
  const float* b_dec  = (const float*)d_in[7];
  const float* Wl01   = (const float*)d_in[8];
  const float* bl01   = (const float*)d_in[9];
  const float* Wr01   = (const float*)d_in[10];
  const float* Wl2    = (const float*)d_in[11];
  const float* bl2    = (const float*)d_in[12];
  const float* Wr2    = (const float*)d_in[13];
  const float* gamma  = (const float*)d_in[14];
  const float* beta   = (const float*)d_in[15];
  float* out = (float*)d_out;

  const int N = in_sizes[2];
  const int E = in_sizes[3];

  char* ws = (char*)d_ws;
  size_t o = 0;
  auto alloc = [&](size_t bytes) -> void* {
    void* p = ws + o;
    o += (bytes + 255) & ~(size_t)255;
    return p;
  };
  int* cnt      = (int*)alloc((size_t)N * 4);
  int* off      = (int*)alloc(((size_t)N + 1) * 4);
  int* pos      = (int*)alloc((size_t)N * 4);
  int* esrc     = (int*)alloc((size_t)E * 4);
  float* enc    = (float*)alloc((size_t)N * 4 * 4);
  ushort* xbf   = (ushort*)alloc((size_t)N * PSTR * 2);
  ushort* hbf   = (ushort*)alloc((size_t)N * PSTR * 2);
  ushort* aggbf = (ushort*)alloc((size_t)N * PSTR * 2);
  ushort* h1bf  = (ushort*)alloc((size_t)N * DIM * 2);
  ushort* img01 = (ushort*)alloc((size_t)2 * IMG1 * 2);
  ushort* img2  = (ushort*)alloc((size_t)IMG2 * 2);
  float* stats2 = (float*)alloc(512 * 4);
  (void)ws_size; (void)n_in; (void)out_size;

  int prep_total = 512 + N + IMG1 * 2 + IMG2 + N * 16;
  prep_kernel<<<(prep_total + 255) / 256, 256, 0, stream>>>(x, Wl01, Wr01, Wl2, Wr2, img01,
                                                            img2, xbf, stats2, cnt, N);
  hist_kernel<<<(E + 255) / 256, 256, 0, stream>>>(ei, conf, cnt, E);
  scan_kernel<<<1, 1024, 0, stream>>>(cnt, off, pos, N);
  fill_kernel<<<(E + 255) / 256, 256, 0, stream>>>(ei, conf, pos, esrc, E);

  const int gemm_blocks = (N + 63) / 64;
  for (int l = 0; l < 3; ++l) {
    const float* We = W_enc + (size_t)l * CLS * 4 * DIM;
    const float* be = b_enc + (size_t)l * CLS * 4;
    const float* Wd = W_dec + (size_t)l * CLS * DIM * 4;
    const float* bd = b_dec + (size_t)l * CLS * DIM;
    if (l == 0) {
      enc_kernel<<<(N + 3) / 4, 256, 0, stream>>>(xbf, labels, We, be, enc, nullptr, nullptr,
                                                  nullptr, nullptr, 1, 0, N);
    } else {
      enc_kernel<<<(N + 3) / 4, 256, 0, stream>>>(h1bf, labels, We, be, enc, hbf,
                                                  stats2 + (l - 1) * 256,
                                                  gamma + (l - 1) * DIM, beta + (l - 1) * DIM,
                                                  0, 1, N);
    }
    agg_kernel<<<(N + 1) / 2, 256, 0, stream>>>(enc, labels, off, esrc, Wd, bd, aggbf, N);
    if (l < 2) {
      linear_mfma<128><<<gemm_blocks, 256, 0, stream>>>(
          aggbf, (l == 0) ? xbf : hbf, img01 + (size_t)l * IMG1, bl01 + (size_t)l * DIM,
          h1bf, nullptr, stats2 + l * 256, N);
    } else {
      linear_mfma<40><<<gemm_blocks, 256, 0, stream>>>(aggbf, hbf, img2, bl2, nullptr, out,
                                                       nullptr, N);
    }
  }
}

// Round 4
// 333.810 us; speedup vs baseline: 1.1965x; 1.1965x over previous
//
#include <hip/hip_runtime.h>

#define DIM 128
#define CLS 40

typedef __attribute__((ext_vector_type(8))) short bf16x8;
typedef __attribute__((ext_vector_type(4))) float f32x4;

__device__ __forceinline__ ushort f2bf(float f) {
  uint u = __float_as_uint(f);
  u += 0x7FFFu + ((u >> 16) & 1u);
  return (ushort)(u >> 16);
}
__device__ __forceinline__ float bf2f(ushort h) {
  return __uint_as_float(((uint)h) << 16);
}

__device__ __forceinline__ void gl16(const void* g, void* l) {
  __builtin_amdgcn_global_load_lds((const __attribute__((address_space(1))) unsigned*)g,
                                   (__attribute__((address_space(3))) unsigned*)l, 16, 0, 0);
}

// B images: img[((kc*2+hl)*BJ + j)*32 + kk], k = kc*32+kk; hl=0 hi, hl=1 lo.
#define IMG1 (8 * 2 * 128 * 32)
#define IMG2 (8 * 2 * 48 * 32)

__device__ __forceinline__ void build_img(ushort* __restrict__ img, const float* __restrict__ Wl,
                                          const float* __restrict__ Wr, int ncol, int BJ, int t) {
  int kk = t & 31;
  int u = t >> 5;
  int j = u % BJ;
  int v = u / BJ;
  int hl = v & 1;
  int kc = v >> 1;
  int k = kc * 32 + kk;
  float val = 0.f;
  if (j < ncol) val = (k < 128) ? Wl[j * 128 + k] : Wr[j * 128 + (k - 128)];
  ushort hi = f2bf(val);
  img[t] = hl ? f2bf(val - bf2f(hi)) : hi;
}

// ---------------- prep: zero stats/cnt, build weight images, convert x -> bf16 ----------------

__global__ void prep_kernel(const float* __restrict__ x, const float* __restrict__ Wl01,
                            const float* __restrict__ Wr01, const float* __restrict__ Wl2,
                            const float* __restrict__ Wr2, ushort* __restrict__ img01,
                            ushort* __restrict__ img2, ushort* __restrict__ xbf,
                            float* __restrict__ stats2, int* __restrict__ cnt, int N) {
  int idx = blockIdx.x * 256 + threadIdx.x;
  int b0 = 512;
  int b1 = b0 + N;
  int b2 = b1 + IMG1;
  int b3 = b2 + IMG1;
  int b4 = b3 + IMG2;
  int b5 = b4 + N * 16;
  if (idx < b0) { stats2[idx] = 0.f; return; }
  if (idx < b1) { cnt[idx - b0] = 0; return; }
  if (idx < b2) { build_img(img01, Wl01, Wr01, 128, 128, idx - b1); return; }
  if (idx < b3) { build_img(img01 + IMG1, Wl01 + 128 * 128, Wr01 + 128 * 128, 128, 128, idx - b2); return; }
  if (idx < b4) { build_img(img2, Wl2, Wr2, 40, 48, idx - b3); return; }
  if (idx < b5) {
    int t = idx - b4;
    int n = t >> 4, part = t & 15;
    const float4* xp = (const float4*)&x[(size_t)n * DIM + part * 8];
    float4 v0 = xp[0], v1 = xp[1];
    union { ushort u[8]; uint4 v; } pk;
    pk.u[0] = f2bf(v0.x); pk.u[1] = f2bf(v0.y); pk.u[2] = f2bf(v0.z); pk.u[3] = f2bf(v0.w);
    pk.u[4] = f2bf(v1.x); pk.u[5] = f2bf(v1.y); pk.u[6] = f2bf(v1.z); pk.u[7] = f2bf(v1.w);
    *(uint4*)&xbf[(size_t)n * DIM + part * 8] = pk.v;
  }
}

// ---------------- CSR build ----------------

__global__ void hist_kernel(const int* __restrict__ ei, const float* __restrict__ conf,
                            int* __restrict__ cnt, int E) {
  int e = blockIdx.x * 256 + threadIdx.x;
  if (e < E && conf[e] > 0.5f) atomicAdd(&cnt[ei[E + e]], 1);
}

__global__ __launch_bounds__(1024) void scan_kernel(const int* __restrict__ cnt,
                                                    int* __restrict__ off,
                                                    int* __restrict__ pos, int n) {
  __shared__ int wsum[16];
  __shared__ int carry_s;
  int lane = threadIdx.x & 63;
  int wid = threadIdx.x >> 6;
  if (threadIdx.x == 0) carry_s = 0;
  __syncthreads();
  int n4 = (n + 3) >> 2;
  for (int base = 0; base < n4; base += 1024) {
    int i4 = base + (int)threadIdx.x;
    int4 v = make_int4(0, 0, 0, 0);
    int i0 = i4 * 4;
    if (i0 + 3 < n) {
      v = *(const int4*)&cnt[i0];
    } else if (i0 < n) {
      v.x = cnt[i0];
      if (i0 + 1 < n) v.y = cnt[i0 + 1];
      if (i0 + 2 < n) v.z = cnt[i0 + 2];
    }
    int s4 = v.x + v.y + v.z + v.w;
    int s = s4;
#pragma unroll
    for (int o = 1; o < 64; o <<= 1) {
      int t = __shfl_up(s, o);
      if (lane >= o) s += t;
    }
    if (lane == 63) wsum[wid] = s;
    __syncthreads();
    if (wid == 0) {
      int w = (lane < 16) ? wsum[lane] : 0;
#pragma unroll
      for (int o = 1; o < 16; o <<= 1) {
        int t = __shfl_up(w, o);
        if (lane >= o) w += t;
      }
      if (lane < 16) wsum[lane] = w;
    }
    __syncthreads();
    int carry = carry_s;
    int wbase = (wid == 0) ? 0 : wsum[wid - 1];
    int excl = carry + wbase + s - s4;
    if (i0 < n) {
      int e0 = excl, e1 = e0 + v.x, e2 = e1 + v.y, e3 = e2 + v.z;
      off[i0] = e0; pos[i0] = e0;
      if (i0 + 1 < n) { off[i0 + 1] = e1; pos[i0 + 1] = e1; }
      if (i0 + 2 < n) { off[i0 + 2] = e2; pos[i0 + 2] = e2; }
      if (i0 + 3 < n) { off[i0 + 3] = e3; pos[i0 + 3] = e3; }
    }
    int tot = wsum[15];
    __syncthreads();
    if (threadIdx.x == 0) carry_s = carry + tot;
    __syncthreads();
  }
  if (threadIdx.x == 0) off[n] = carry_s;
}

__global__ void fill_kernel(const int* __restrict__ ei, const float* __restrict__ conf,
                            int* __restrict__ pos, int* __restrict__ esrc, int E) {
  int e = blockIdx.x * 256 + threadIdx.x;
  if (e < E && conf[e] > 0.5f) {
    int p = atomicAdd(&pos[ei[E + e]], 1);
    esrc[p] = ei[e];
  }
}

// ---------------- enc (+ fused BN+relu of previous linear output) ----------------

__global__ __launch_bounds__(256) void enc_kernel(const ushort* __restrict__ src,
                                                  const int* __restrict__ labels,
                                                  const float* __restrict__ We,
                                                  const float* __restrict__ be,
                                                  float* __restrict__ enc,
                                                  ushort* __restrict__ hbf,
                                                  const float* __restrict__ stats,
                                                  const float* __restrict__ gamma,
                                                  const float* __restrict__ beta,
                                                  int useBN, int N) {
  int wid = threadIdx.x >> 6;
  int lane = threadIdx.x & 63;
  int n = blockIdx.x * 4 + wid;
  if (n >= N) return;
  int c = labels[n];
  int sc = c < 0 ? 0 : c;
  int d0 = lane, d1 = 64 + lane;
  size_t base = (size_t)n * DIM;
  float h0 = bf2f(src[base + d0]);
  float h1 = bf2f(src[base + d1]);
  if (useBN) {
    float inv = 1.f / (float)N;
    float mu0 = stats[d0] * inv, mu1 = stats[d1] * inv;
    float va0 = stats[DIM + d0] * inv - mu0 * mu0;
    float va1 = stats[DIM + d1] * inv - mu1 * mu1;
    h0 = fmaxf(fmaf(gamma[d0] * (h0 - mu0), rsqrtf(va0 + 1e-5f), beta[d0]), 0.f);
    h1 = fmaxf(fmaf(gamma[d1] * (h1 - mu1), rsqrtf(va1 + 1e-5f), beta[d1]), 0.f);
    hbf[base + d0] = f2bf(h0);
    hbf[base + d1] = f2bf(h1);
  }
  const float* wb = We + (size_t)sc * 4 * DIM;
  float p0 = wb[0 * DIM + lane] * h0 + wb[0 * DIM + 64 + lane] * h1;
  float p1 = wb[1 * DIM + lane] * h0 + wb[1 * DIM + 64 + lane] * h1;
  float p2 = wb[2 * DIM + lane] * h0 + wb[2 * DIM + 64 + lane] * h1;
  float p3 = wb[3 * DIM + lane] * h0 + wb[3 * DIM + 64 + lane] * h1;
#pragma unroll
  for (int o = 32; o > 0; o >>= 1) {
    p0 += __shfl_xor(p0, o);
    p1 += __shfl_xor(p1, o);
    p2 += __shfl_xor(p2, o);
    p3 += __shfl_xor(p3, o);
  }
  if (lane == 0) {
    const float* bb = be + sc * 4;
    float4 r;
    r.x = (c < 0) ? 0.f : fmaxf(p0 + bb[0], 0.f);
    r.y = (c < 0) ? 0.f : fmaxf(p1 + bb[1], 0.f);
    r.z = (c < 0) ? 0.f : fmaxf(p2 + bb[2], 0.f);
    r.w = (c < 0) ? 0.f : fmaxf(p3 + bb[3], 0.f);
    *(float4*)&enc[n * 4] = r;
  }
}

// ---------------- agg: scatter-mean of routed decoder over selected edges ----------------

__global__ __launch_bounds__(256) void agg_kernel(const float* __restrict__ enc,
                                                  const int* __restrict__ labels,
                                                  const int* __restrict__ off,
                                                  const int* __restrict__ esrc,
                                                  const float* __restrict__ Wd,
                                                  const float* __restrict__ bd,
                                                  ushort* __restrict__ aggbf, int N) {
  int half = threadIdx.x >> 7;
  int d = threadIdx.x & 127;
  int n = blockIdx.x * 2 + half;
  if (n >= N) return;
  int c = labels[n];
  int j0 = off[n], j1 = off[n + 1];
  int cnt = j1 - j0;
  float outv = 0.f;
  if (c >= 0 && cnt > 0) {
    const float4 w = *(const float4*)&Wd[((size_t)c * DIM + d) * 4];
    const float bb = bd[(size_t)c * DIM + d];
    float acc = 0.f;
    for (int j = j0; j < j1; ++j) {
      int s = esrc[j];
      float4 m = *(const float4*)&enc[s * 4];
      float v = fmaf(w.x, m.x, fmaf(w.y, m.y, fmaf(w.z, m.z, fmaf(w.w, m.w, bb))));
      acc += fmaxf(v, 0.f);
    }
    outv = acc / (float)cnt;
  }
  aggbf[(size_t)n * DIM + d] = f2bf(outv);
}

// ---------------- GEMM: weight-stationary, stream-A, barrier-free K-loop ----------------
// B (split hi/lo) staged to LDS once per block via global_load_lds (one barrier).
// A fragments loaded global->VGPR directly; grid-stride over 128-row tiles.

template <int NCOL>
__global__ __launch_bounds__(256, NCOL == 128 ? 1 : 2) void linear_ws(
    const ushort* __restrict__ Abf, const ushort* __restrict__ Hbf,
    const ushort* __restrict__ img, const float* __restrict__ bias,
    ushort* __restrict__ h1bf, float* __restrict__ outf,
    float* __restrict__ stats, int N, int ntiles) {
  constexpr int BJ = (NCOL == 128) ? 128 : 48;
  constexpr int MF = (NCOL == 128) ? 4 : 2;
  constexpr int NF = (NCOL == 128) ? 4 : 3;
  constexpr int BELEMS = 8 * 2 * BJ * 32;  // 128KB / 48KB
  __shared__ __align__(16) ushort Blds[BELEMS];
  const int tid = threadIdx.x;
  const int w = tid >> 6, l = tid & 63;
  constexpr int NBLD = BELEMS * 2 / 16;
#pragma unroll
  for (int i = 0; i < NBLD / 256; ++i)
    gl16((const char*)img + (size_t)(i * 256 + tid) * 16, (char*)Blds + (i * 256 + tid) * 16);
  __syncthreads();

  const int wrow = (NCOL == 128) ? (w & 1) * 64 : w * 32;
  const int wcol = (NCOL == 128) ? (w >> 1) * 64 : 0;
  const int cc = l & 15, q = l >> 4;

  for (int t = blockIdx.x; t < ntiles; t += gridDim.x) {
    const int r0 = t * 128;
    bf16x8 a[8][MF];
#pragma unroll
    for (int kc = 0; kc < 8; ++kc) {
      const ushort* src = (kc < 4) ? Abf : Hbf;
#pragma unroll
      for (int m = 0; m < MF; ++m) {
        int row = r0 + wrow + m * 16 + cc;
        row = row < N ? row : N - 1;
        a[kc][m] = *(const bf16x8*)((const char*)src + (size_t)row * 256 + (kc & 3) * 64 + q * 16);
      }
    }
    f32x4 acc[MF][NF];
#pragma unroll
    for (int m = 0; m < MF; ++m)
#pragma unroll
      for (int n = 0; n < NF; ++n) acc[m][n] = (f32x4){0.f, 0.f, 0.f, 0.f};

#pragma unroll
    for (int kc = 0; kc < 8; ++kc) {
#pragma unroll
      for (int n = 0; n < NF; ++n) {
        int col = wcol + n * 16 + cc;
        const ushort* bp = &Blds[((kc * 2) * BJ + col) * 32 + q * 8];
        bf16x8 bh = *(const bf16x8*)bp;
        bf16x8 bl = *(const bf16x8*)(bp + BJ * 32);
#pragma unroll
        for (int m = 0; m < MF; ++m) {
          acc[m][n] = __builtin_amdgcn_mfma_f32_16x16x32_bf16(a[kc][m], bh, acc[m][n], 0, 0, 0);
          acc[m][n] = __builtin_amdgcn_mfma_f32_16x16x32_bf16(a[kc][m], bl, acc[m][n], 0, 0, 0);
        }
      }
    }

    if constexpr (NCOL == 128) {
#pragma unroll
      for (int n = 0; n < NF; ++n) {
        int col = wcol + n * 16 + cc;
        float bv = bias[col];
        float s = 0.f, q2 = 0.f;
#pragma unroll
        for (int m = 0; m < MF; ++m) {
#pragma unroll
          for (int r = 0; r < 4; ++r) {
            int row = r0 + wrow + m * 16 + q * 4 + r;
            if (row < N) {
              float v = acc[m][n][r] + bv;
              h1bf[(size_t)row * DIM + col] = f2bf(v);
              s += v;
              q2 = fmaf(v, v, q2);
            }
          }
        }
        s += __shfl_xor(s, 16); s += __shfl_xor(s, 32);
        q2 += __shfl_xor(q2, 16); q2 += __shfl_xor(q2, 32);
        if (l < 16) {
          atomicAdd(&stats[col], s);
          atomicAdd(&stats[DIM + col], q2);
        }
      }
    } else {
#pragma unroll
      for (int n = 0; n < NF; ++n) {
        int col = n * 16 + cc;
        if (col < NCOL) {
          float bv = bias[col];
#pragma unroll
          for (int m = 0; m < MF; ++m) {
#pragma unroll
            for (int r = 0; r < 4; ++r) {
              int row = r0 + wrow + m * 16 + q * 4 + r;
              if (row < N) outf[(size_t)row * NCOL + col] = acc[m][n][r] + bv;
            }
          }
        }
      }
    }
  }
}

// ---------------- host ----------------

extern "C" void kernel_launch(void* const* d_in, const int* in_sizes, int n_in,
                              void* d_out, int out_size, void* d_ws, size_t ws_size,
                              hipStream_t stream) {
  const float* x      = (const float*)d_in[0];
  const int*   ei     = (const int*)d_in[1];
  const int*   labels = (const int*)d_in[2];
  const float* conf   = (const float*)d_in[3];
  const float* W_enc  = (const float*)d_in[4];
  const float* b_enc  = (const float*)d_in[5];
  const float* W_dec  = (const float*)d_in[6];
  const float* b_dec  = (const float*)d_in[7];
  const float* Wl01   = (const float*)d_in[8];
  const float* bl01   = (const float*)d_in[9];
  const float* Wr01   = (const float*)d_in[10];
  const float* Wl2    = (const float*)d_in[11];
  const float* bl2    = (const float*)d_in[12];
  const float* Wr2    = (const float*)d_in[13];
  const float* gamma  = (const float*)d_in[14];
  const float* beta   = (const float*)d_in[15];
  float* out = (float*)d_out;

  const int N = in_sizes[2];
  const int E = in_sizes[3];

  char* ws = (char*)d_ws;
  size_t o = 0;
  auto alloc = [&](size_t bytes) -> void* {
    void* p = ws + o;
    o += (bytes + 255) & ~(size_t)255;
    return p;
  };
  int* cnt      = (int*)alloc((size_t)N * 4);
  int* off      = (int*)alloc(((size_t)N + 1) * 4);
  int* pos      = (int*)alloc((size_t)N * 4);
  int* esrc     = (int*)alloc((size_t)E * 4);
  float* enc    = (float*)alloc((size_t)N * 4 * 4);
  ushort* xbf   = (ushort*)alloc((size_t)N * DIM * 2);
  ushort* hbf   = (ushort*)alloc((size_t)N * DIM * 2);
  ushort* aggbf = (ushort*)alloc((size_t)N * DIM * 2);
  ushort* h1bf  = (ushort*)alloc((size_t)N * DIM * 2);
  ushort* img01 = (ushort*)alloc((size_t)2 * IMG1 * 2);
  ushort* img2  = (ushort*)alloc((size_t)IMG2 * 2);
  float* stats2 = (float*)alloc(512 * 4);
  (void)ws_size; (void)n_in; (void)out_size;

  int prep_total = 512 + N + IMG1 * 2 + IMG2 + N * 16;
  prep_kernel<<<(prep_total + 255) / 256, 256, 0, stream>>>(x, Wl01, Wr01, Wl2, Wr2, img01,
                                                            img2, xbf, stats2, cnt, N);
  hist_kernel<<<(E + 255) / 256, 256, 0, stream>>>(ei, conf, cnt, E);
  scan_kernel<<<1, 1024, 0, stream>>>(cnt, off, pos, N);
  fill_kernel<<<(E + 255) / 256, 256, 0, stream>>>(ei, conf, pos, esrc, E);

  const int ntiles = (N + 127) / 128;
  for (int l = 0; l < 3; ++l) {
    const float* We = W_enc + (size_t)l * CLS * 4 * DIM;
    const float* be = b_enc + (size_t)l * CLS * 4;
    const float* Wd = W_dec + (size_t)l * CLS * DIM * 4;
    const float* bd = b_dec + (size_t)l * CLS * DIM;
    if (l == 0) {
      enc_kernel<<<(N + 3) / 4, 256, 0, stream>>>(xbf, labels, We, be, enc, nullptr, nullptr,
                                                  nullptr, nullptr, 0, N);
    } else {
      enc_kernel<<<(N + 3) / 4, 256, 0, stream>>>(h1bf, labels, We, be, enc, hbf,
                                                  stats2 + (l - 1) * 256,
                                                  gamma + (l - 1) * DIM, beta + (l - 1) * DIM,
                                                  1, N);
    }
    agg_kernel<<<(N + 1) / 2, 256, 0, stream>>>(enc, labels, off, esrc, Wd, bd, aggbf, N);
    if (l < 2) {
      linear_ws<128><<<256, 256, 0, stream>>>(aggbf, (l == 0) ? xbf : hbf,
                                              img01 + (size_t)l * IMG1, bl01 + (size_t)l * DIM,
                                              h1bf, nullptr, stats2 + l * 256, N, ntiles);
    } else {
      linear_ws<40><<<ntiles, 256, 0, stream>>>(aggbf, hbf, img2, bl2, nullptr, out,
                                                nullptr, N, ntiles);
    }
  }
}

// Round 5
// 240.129 us; speedup vs baseline: 1.6632x; 1.3901x over previous
//
#include <hip/hip_runtime.h>

#define DIM 128
#define CLS 40

typedef __attribute__((ext_vector_type(8))) short bf16x8;
typedef __attribute__((ext_vector_type(4))) float f32x4;

__device__ __forceinline__ ushort f2bf(float f) {
  uint u = __float_as_uint(f);
  u += 0x7FFFu + ((u >> 16) & 1u);
  return (ushort)(u >> 16);
}
__device__ __forceinline__ float bf2f(ushort h) {
  return __uint_as_float(((uint)h) << 16);
}

__device__ __forceinline__ void gl16(const void* g, void* l) {
  __builtin_amdgcn_global_load_lds((const __attribute__((address_space(1))) unsigned*)g,
                                   (__attribute__((address_space(3))) unsigned*)l, 16, 0, 0);
}

// B images, fragment-contiguous: t = f*512 + l*8 + j, f = (kc*2+hl)*NCG + cg.
// Lane l of fragment f holds W[col = cg*16 + (l&15)][k = kc*32 + (l>>4)*8 + j].
#define IMG1 (8 * 2 * 8 * 512)   // NCOL=128 (NCG=8) -> 65536 elems = 128KB
#define IMG2 (8 * 2 * 3 * 512)   // NCOL=40  (NCG=3) -> 24576 elems = 48KB

__device__ __forceinline__ void build_img(ushort* __restrict__ img, const float* __restrict__ Wl,
                                          const float* __restrict__ Wr, int ncol, int NCG, int t) {
  int j = t & 7;
  int lq = (t >> 3) & 63;
  int f = t >> 9;
  int cg = f % NCG;
  int u = f / NCG;
  int hl = u & 1;
  int kc = u >> 1;
  int col = cg * 16 + (lq & 15);
  int k = kc * 32 + (lq >> 4) * 8 + j;
  float val = (col < ncol) ? ((k < 128) ? Wl[col * 128 + k] : Wr[col * 128 + (k - 128)]) : 0.f;
  ushort hi = f2bf(val);
  img[t] = hl ? f2bf(val - bf2f(hi)) : hi;
}

// ---------------- prep: zero stats/cnt, build weight images, convert x -> bf16 ----------------

__global__ void prep_kernel(const float* __restrict__ x, const float* __restrict__ Wl01,
                            const float* __restrict__ Wr01, const float* __restrict__ Wl2,
                            const float* __restrict__ Wr2, ushort* __restrict__ img01,
                            ushort* __restrict__ img2, ushort* __restrict__ xbf,
                            float* __restrict__ stats2, int* __restrict__ cnt, int N) {
  int idx = blockIdx.x * 256 + threadIdx.x;
  int b0 = 512;
  int b1 = b0 + N;
  int b2 = b1 + IMG1;
  int b3 = b2 + IMG1;
  int b4 = b3 + IMG2;
  int b5 = b4 + N * 16;
  if (idx < b0) { stats2[idx] = 0.f; return; }
  if (idx < b1) { cnt[idx - b0] = 0; return; }
  if (idx < b2) { build_img(img01, Wl01, Wr01, 128, 8, idx - b1); return; }
  if (idx < b3) { build_img(img01 + IMG1, Wl01 + 128 * 128, Wr01 + 128 * 128, 128, 8, idx - b2); return; }
  if (idx < b4) { build_img(img2, Wl2, Wr2, 40, 3, idx - b3); return; }
  if (idx < b5) {
    int t = idx - b4;
    int n = t >> 4, part = t & 15;
    const float4* xp = (const float4*)&x[(size_t)n * DIM + part * 8];
    float4 v0 = xp[0], v1 = xp[1];
    union { ushort u[8]; uint4 v; } pk;
    pk.u[0] = f2bf(v0.x); pk.u[1] = f2bf(v0.y); pk.u[2] = f2bf(v0.z); pk.u[3] = f2bf(v0.w);
    pk.u[4] = f2bf(v1.x); pk.u[5] = f2bf(v1.y); pk.u[6] = f2bf(v1.z); pk.u[7] = f2bf(v1.w);
    *(uint4*)&xbf[(size_t)n * DIM + part * 8] = pk.v;
  }
}

// ---------------- CSR build ----------------

__global__ void hist_kernel(const int* __restrict__ ei, const float* __restrict__ conf,
                            int* __restrict__ cnt, int E) {
  int e = blockIdx.x * 256 + threadIdx.x;
  if (e < E && conf[e] > 0.5f) atomicAdd(&cnt[ei[E + e]], 1);
}

__global__ __launch_bounds__(1024) void scan_kernel(const int* __restrict__ cnt,
                                                    int* __restrict__ off,
                                                    int* __restrict__ pos, int n) {
  __shared__ int wsum[16];
  __shared__ int carry_s;
  int lane = threadIdx.x & 63;
  int wid = threadIdx.x >> 6;
  if (threadIdx.x == 0) carry_s = 0;
  __syncthreads();
  int n4 = (n + 3) >> 2;
  for (int base = 0; base < n4; base += 1024) {
    int i4 = base + (int)threadIdx.x;
    int4 v = make_int4(0, 0, 0, 0);
    int i0 = i4 * 4;
    if (i0 + 3 < n) {
      v = *(const int4*)&cnt[i0];
    } else if (i0 < n) {
      v.x = cnt[i0];
      if (i0 + 1 < n) v.y = cnt[i0 + 1];
      if (i0 + 2 < n) v.z = cnt[i0 + 2];
    }
    int s4 = v.x + v.y + v.z + v.w;
    int s = s4;
#pragma unroll
    for (int o = 1; o < 64; o <<= 1) {
      int t = __shfl_up(s, o);
      if (lane >= o) s += t;
    }
    if (lane == 63) wsum[wid] = s;
    __syncthreads();
    if (wid == 0) {
      int w = (lane < 16) ? wsum[lane] : 0;
#pragma unroll
      for (int o = 1; o < 16; o <<= 1) {
        int t = __shfl_up(w, o);
        if (lane >= o) w += t;
      }
      if (lane < 16) wsum[lane] = w;
    }
    __syncthreads();
    int carry = carry_s;
    int wbase = (wid == 0) ? 0 : wsum[wid - 1];
    int excl = carry + wbase + s - s4;
    if (i0 < n) {
      int e0 = excl, e1 = e0 + v.x, e2 = e1 + v.y, e3 = e2 + v.z;
      off[i0] = e0; pos[i0] = e0;
      if (i0 + 1 < n) { off[i0 + 1] = e1; pos[i0 + 1] = e1; }
      if (i0 + 2 < n) { off[i0 + 2] = e2; pos[i0 + 2] = e2; }
      if (i0 + 3 < n) { off[i0 + 3] = e3; pos[i0 + 3] = e3; }
    }
    int tot = wsum[15];
    __syncthreads();
    if (threadIdx.x == 0) carry_s = carry + tot;
    __syncthreads();
  }
  if (threadIdx.x == 0) off[n] = carry_s;
}

__global__ void fill_kernel(const int* __restrict__ ei, const float* __restrict__ conf,
                            int* __restrict__ pos, int* __restrict__ esrc, int E) {
  int e = blockIdx.x * 256 + threadIdx.x;
  if (e < E && conf[e] > 0.5f) {
    int p = atomicAdd(&pos[ei[E + e]], 1);
    esrc[p] = ei[e];
  }
}

// ---------------- enc (+ fused BN+relu of previous linear output) ----------------

__global__ __launch_bounds__(256) void enc_kernel(const ushort* __restrict__ src,
                                                  const int* __restrict__ labels,
                                                  const float* __restrict__ We,
                                                  const float* __restrict__ be,
                                                  float* __restrict__ enc,
                                                  ushort* __restrict__ hbf,
                                                  const float* __restrict__ stats,
                                                  const float* __restrict__ gamma,
                                                  const float* __restrict__ beta,
                                                  int useBN, int N) {
  int wid = threadIdx.x >> 6;
  int lane = threadIdx.x & 63;
  int n = blockIdx.x * 4 + wid;
  if (n >= N) return;
  int c = labels[n];
  int sc = c < 0 ? 0 : c;
  int d0 = lane, d1 = 64 + lane;
  size_t base = (size_t)n * DIM;
  float h0 = bf2f(src[base + d0]);
  float h1 = bf2f(src[base + d1]);
  if (useBN) {
    float inv = 1.f / (float)N;
    float mu0 = stats[d0] * inv, mu1 = stats[d1] * inv;
    float va0 = stats[DIM + d0] * inv - mu0 * mu0;
    float va1 = stats[DIM + d1] * inv - mu1 * mu1;
    h0 = fmaxf(fmaf(gamma[d0] * (h0 - mu0), rsqrtf(va0 + 1e-5f), beta[d0]), 0.f);
    h1 = fmaxf(fmaf(gamma[d1] * (h1 - mu1), rsqrtf(va1 + 1e-5f), beta[d1]), 0.f);
    hbf[base + d0] = f2bf(h0);
    hbf[base + d1] = f2bf(h1);
  }
  const float* wb = We + (size_t)sc * 4 * DIM;
  float p0 = wb[0 * DIM + lane] * h0 + wb[0 * DIM + 64 + lane] * h1;
  float p1 = wb[1 * DIM + lane] * h0 + wb[1 * DIM + 64 + lane] * h1;
  float p2 = wb[2 * DIM + lane] * h0 + wb[2 * DIM + 64 + lane] * h1;
  float p3 = wb[3 * DIM + lane] * h0 + wb[3 * DIM + 64 + lane] * h1;
#pragma unroll
  for (int o = 32; o > 0; o >>= 1) {
    p0 += __shfl_xor(p0, o);
    p1 += __shfl_xor(p1, o);
    p2 += __shfl_xor(p2, o);
    p3 += __shfl_xor(p3, o);
  }
  if (lane == 0) {
    const float* bb = be + sc * 4;
    float4 r;
    r.x = (c < 0) ? 0.f : fmaxf(p0 + bb[0], 0.f);
    r.y = (c < 0) ? 0.f : fmaxf(p1 + bb[1], 0.f);
    r.z = (c < 0) ? 0.f : fmaxf(p2 + bb[2], 0.f);
    r.w = (c < 0) ? 0.f : fmaxf(p3 + bb[3], 0.f);
    *(float4*)&enc[n * 4] = r;
  }
}

// ---------------- agg: one wave per node; batched edge loads ----------------

__global__ __launch_bounds__(256) void agg_kernel(const float* __restrict__ enc,
                                                  const int* __restrict__ labels,
                                                  const int* __restrict__ off,
                                                  const int* __restrict__ esrc,
                                                  const float* __restrict__ Wd,
                                                  const float* __restrict__ bd,
                                                  ushort* __restrict__ aggbf, int N) {
  int wid = threadIdx.x >> 6;
  int lane = threadIdx.x & 63;
  int n = blockIdx.x * 4 + wid;
  if (n >= N) return;
  int c = labels[n];
  int j0 = off[n], j1 = off[n + 1];
  int cnt = j1 - j0;
  float acc0 = 0.f, acc1 = 0.f;
  if (c >= 0 && cnt > 0) {
    const float4 w0 = *(const float4*)&Wd[((size_t)c * DIM + lane) * 4];
    const float4 w1 = *(const float4*)&Wd[((size_t)c * DIM + 64 + lane) * 4];
    const float b0 = bd[(size_t)c * DIM + lane];
    const float b1 = bd[(size_t)c * DIM + 64 + lane];
    for (int jb = j0; jb < j1; jb += 64) {
      int nn = min(64, j1 - jb);
      int sreg = (lane < nn) ? esrc[jb + lane] : 0;
      for (int u = 0; u < nn; u += 8) {
        int m = min(8, nn - u);
        float4 mv0, mv1, mv2, mv3, mv4, mv5, mv6, mv7;
        int s0 = __shfl(sreg, u + 0), s1 = __shfl(sreg, u + 1);
        int s2 = __shfl(sreg, u + 2), s3 = __shfl(sreg, u + 3);
        int s4 = __shfl(sreg, u + 4), s5 = __shfl(sreg, u + 5);
        int s6 = __shfl(sreg, u + 6), s7 = __shfl(sreg, u + 7);
        mv0 = *(const float4*)&enc[s0 * 4];
        if (m > 1) mv1 = *(const float4*)&enc[s1 * 4];
        if (m > 2) mv2 = *(const float4*)&enc[s2 * 4];
        if (m > 3) mv3 = *(const float4*)&enc[s3 * 4];
        if (m > 4) mv4 = *(const float4*)&enc[s4 * 4];
        if (m > 5) mv5 = *(const float4*)&enc[s5 * 4];
        if (m > 6) mv6 = *(const float4*)&enc[s6 * 4];
        if (m > 7) mv7 = *(const float4*)&enc[s7 * 4];
#define DO_EDGE(mv)                                                                       \
  {                                                                                       \
    float v0 = fmaf(w0.x, mv.x, fmaf(w0.y, mv.y, fmaf(w0.z, mv.z, fmaf(w0.w, mv.w, b0)))); \
    float v1 = fmaf(w1.x, mv.x, fmaf(w1.y, mv.y, fmaf(w1.z, mv.z, fmaf(w1.w, mv.w, b1)))); \
    acc0 += fmaxf(v0, 0.f);                                                               \
    acc1 += fmaxf(v1, 0.f);                                                               \
  }
        DO_EDGE(mv0);
        if (m > 1) DO_EDGE(mv1);
        if (m > 2) DO_EDGE(mv2);
        if (m > 3) DO_EDGE(mv3);
        if (m > 4) DO_EDGE(mv4);
        if (m > 5) DO_EDGE(mv5);
        if (m > 6) DO_EDGE(mv6);
        if (m > 7) DO_EDGE(mv7);
#undef DO_EDGE
      }
    }
    float invc = 1.f / (float)cnt;
    acc0 *= invc;
    acc1 *= invc;
  }
  aggbf[(size_t)n * DIM + lane] = f2bf(acc0);
  aggbf[(size_t)n * DIM + 64 + lane] = f2bf(acc1);
}

// ---------------- GEMM: weight-stationary LDS B (fragment-contiguous), 512-thr blocks ----------------
// tile 256 rows; NCOL=128: wave grid 4x2, MF=4, NF=4; NCOL=40: 8x1, MF=2, NF=3.

template <int NCOL>
__global__ __launch_bounds__(512, 2) void linear_ws(
    const ushort* __restrict__ Abf, const ushort* __restrict__ Hbf,
    const ushort* __restrict__ img, const float* __restrict__ bias,
    ushort* __restrict__ h1bf, float* __restrict__ outf,
    float* __restrict__ stats, int N) {
  constexpr int NCG = (NCOL == 128) ? 8 : 3;
  constexpr int MF = (NCOL == 128) ? 4 : 2;
  constexpr int NF = (NCOL == 128) ? 4 : 3;
  constexpr int BELEMS = 8 * 2 * NCG * 512;
  __shared__ __align__(16) ushort Blds[BELEMS];
  __shared__ float stats_l[256];
  const int tid = threadIdx.x;
  const int w = tid >> 6, l = tid & 63;
  const int cc = l & 15, q = l >> 4;
  const int r0 = blockIdx.x * 256;
  const int wrow = (NCOL == 128) ? (w & 3) * 64 : w * 32;
  const int wcolg = (NCOL == 128) ? (w >> 2) * 4 : 0;  // column group (16-col units)

  if (NCOL == 128 && tid < 256) stats_l[tid] = 0.f;
  constexpr int NBLD = BELEMS * 2 / 16;
#pragma unroll
  for (int i = 0; i < NBLD / 512; ++i)
    gl16((const char*)img + (size_t)(i * 512 + tid) * 16, (char*)Blds + (i * 512 + tid) * 16);
  __syncthreads();

  f32x4 acc[MF][NF];
#pragma unroll
  for (int m = 0; m < MF; ++m)
#pragma unroll
    for (int n = 0; n < NF; ++n) acc[m][n] = (f32x4){0.f, 0.f, 0.f, 0.f};

#pragma unroll
  for (int kc = 0; kc < 8; ++kc) {
    const ushort* srcA = (kc < 4) ? Abf : Hbf;
    bf16x8 a[MF];
#pragma unroll
    for (int m = 0; m < MF; ++m) {
      int row = r0 + wrow + m * 16 + cc;
      row = row < N ? row : N - 1;
      a[m] = *(const bf16x8*)((const char*)srcA + (size_t)row * 256 + (kc & 3) * 64 + q * 16);
    }
#pragma unroll
    for (int hl = 0; hl < 2; ++hl) {
#pragma unroll
      for (int n = 0; n < NF; ++n) {
        int f = (kc * 2 + hl) * NCG + wcolg + n;
        bf16x8 b = *(const bf16x8*)((const char*)Blds + ((size_t)f << 10) + (l << 4));
#pragma unroll
        for (int m = 0; m < MF; ++m)
          acc[m][n] = __builtin_amdgcn_mfma_f32_16x16x32_bf16(a[m], b, acc[m][n], 0, 0, 0);
      }
    }
  }

  if constexpr (NCOL == 128) {
#pragma unroll
    for (int n = 0; n < NF; ++n) {
      int col = wcolg * 16 + n * 16 + cc;
      float bv = bias[col];
      float s = 0.f, q2 = 0.f;
#pragma unroll
      for (int m = 0; m < MF; ++m) {
#pragma unroll
        for (int r = 0; r < 4; ++r) {
          int row = r0 + wrow + m * 16 + q * 4 + r;
          if (row < N) {
            float v = acc[m][n][r] + bv;
            h1bf[(size_t)row * DIM + col] = f2bf(v);
            s += v;
            q2 = fmaf(v, v, q2);
          }
        }
      }
      s += __shfl_xor(s, 16); s += __shfl_xor(s, 32);
      q2 += __shfl_xor(q2, 16); q2 += __shfl_xor(q2, 32);
      if (l < 16) {
        atomicAdd(&stats_l[col], s);
        atomicAdd(&stats_l[DIM + col], q2);
      }
    }
    __syncthreads();
    if (tid < 256) atomicAdd(&stats[tid], stats_l[tid]);
  } else {
#pragma unroll
    for (int n = 0; n < NF; ++n) {
      int col = n * 16 + cc;
      if (col < NCOL) {
        float bv = bias[col];
#pragma unroll
        for (int m = 0; m < MF; ++m) {
#pragma unroll
          for (int r = 0; r < 4; ++r) {
            int row = r0 + wrow + m * 16 + q * 4 + r;
            if (row < N) outf[(size_t)row * NCOL + col] = acc[m][n][r] + bv;
          }
        }
      }
    }
  }
}

// ---------------- host ----------------

extern "C" void kernel_launch(void* const* d_in, const int* in_sizes, int n_in,
                              void* d_out, int out_size, void* d_ws, size_t ws_size,
                              hipStream_t stream) {
  const float* x      = (const float*)d_in[0];
  const int*   ei     = (const int*)d_in[1];
  const int*   labels = (const int*)d_in[2];
  const float* conf   = (const float*)d_in[3];
  const float* W_enc  = (const float*)d_in[4];
  const float* b_enc  = (const float*)d_in[5];
  const float* W_dec  = (const float*)d_in[6];
  const float* b_dec  = (const float*)d_in[7];
  const float* Wl01   = (const float*)d_in[8];
  const float* bl01   = (const float*)d_in[9];
  const float* Wr01   = (const float*)d_in[10];
  const float* Wl2    = (const float*)d_in[11];
  const float* bl2    = (const float*)d_in[12];
  const float* Wr2    = (const float*)d_in[13];
  const float* gamma  = (const float*)d_in[14];
  const float* beta   = (const float*)d_in[15];
  float* out = (float*)d_out;

  const int N = in_sizes[2];
  const int E = in_sizes[3];

  char* ws = (char*)d_ws;
  size_t o = 0;
  auto alloc = [&](size_t bytes) -> void* {
    void* p = ws + o;
    o += (bytes + 255) & ~(size_t)255;
    return p;
  };
  int* cnt      = (int*)alloc((size_t)N * 4);
  int* off      = (int*)alloc(((size_t)N + 1) * 4);
  int* pos      = (int*)alloc((size_t)N * 4);
  int* esrc     = (int*)alloc((size_t)E * 4);
  float* enc    = (float*)alloc((size_t)N * 4 * 4);
  ushort* xbf   = (ushort*)alloc((size_t)N * DIM * 2);
  ushort* hbf   = (ushort*)alloc((size_t)N * DIM * 2);
  ushort* aggbf = (ushort*)alloc((size_t)N * DIM * 2);
  ushort* h1bf  = (ushort*)alloc((size_t)N * DIM * 2);
  ushort* img01 = (ushort*)alloc((size_t)2 * IMG1 * 2);
  ushort* img2  = (ushort*)alloc((size_t)IMG2 * 2);
  float* stats2 = (float*)alloc(512 * 4);
  (void)ws_size; (void)n_in; (void)out_size;

  int prep_total = 512 + N + IMG1 * 2 + IMG2 + N * 16;
  prep_kernel<<<(prep_total + 255) / 256, 256, 0, stream>>>(x, Wl01, Wr01, Wl2, Wr2, img01,
                                                            img2, xbf, stats2, cnt, N);
  hist_kernel<<<(E + 255) / 256, 256, 0, stream>>>(ei, conf, cnt, E);
  scan_kernel<<<1, 1024, 0, stream>>>(cnt, off, pos, N);
  fill_kernel<<<(E + 255) / 256, 256, 0, stream>>>(ei, conf, pos, esrc, E);

  const int ntiles = (N + 255) / 256;
  for (int l = 0; l < 3; ++l) {
    const float* We = W_enc + (size_t)l * CLS * 4 * DIM;
    const float* be = b_enc + (size_t)l * CLS * 4;
    const float* Wd = W_dec + (size_t)l * CLS * DIM * 4;
    const float* bd = b_dec + (size_t)l * CLS * DIM;
    if (l == 0) {
      enc_kernel<<<(N + 3) / 4, 256, 0, stream>>>(xbf, labels, We, be, enc, nullptr, nullptr,
                                                  nullptr, nullptr, 0, N);
    } else {
      enc_kernel<<<(N + 3) / 4, 256, 0, stream>>>(h1bf, labels, We, be, enc, hbf,
                                                  stats2 + (l - 1) * 256,
                                                  gamma + (l - 1) * DIM, beta + (l - 1) * DIM,
                                                  1, N);
    }
    agg_kernel<<<(N + 3) / 4, 256, 0, stream>>>(enc, labels, off, esrc, Wd, bd, aggbf, N);
    if (l < 2) {
      linear_ws<128><<<ntiles, 512, 0, stream>>>(aggbf, (l == 0) ? xbf : hbf,
                                                 img01 + (size_t)l * IMG1, bl01 + (size_t)l * DIM,
                                                 h1bf, nullptr, stats2 + l * 256, N);
    } else {
      linear_ws<40><<<ntiles, 512, 0, stream>>>(aggbf, hbf, img2, bl2, nullptr, out,
                                                nullptr, N);
    }
  }
}